// Round 2
// baseline (320.871 us; speedup 1.0000x reference)
//
#include <hip/hip_runtime.h>
#include <hip/hip_bf16.h>

// Graph mean aggregation, pull-style:
//   1) deg histogram over dst (int atomics, 1.6M)
//   2) exclusive prefix sum of deg -> offsets (3 small scan kernels)
//   3) bucket scatter: srcs_sorted[atomicAdd(cursor[dst])] = src   (1.6M int atomics)
//   4) gather: per node, sum h[srcs_sorted[off[n]..off[n+1])] and divide by deg
// This removes the 51.2M device-scope float atomics (250MB HBM write traffic)
// of the naive scatter version.

#define D_FEAT 32
#define SCAN_BLOCK 256
#define SCAN_CHUNK 1024   // SCAN_BLOCK threads x 4 elements each

__global__ void zero_i32_kernel(int* __restrict__ p, int n) {
    for (int i = blockIdx.x * blockDim.x + threadIdx.x; i < n;
         i += gridDim.x * blockDim.x) p[i] = 0;
}

__global__ void degree_kernel(const int* __restrict__ dst, int* __restrict__ deg,
                              int n_edges) {
    for (int i = blockIdx.x * blockDim.x + threadIdx.x; i < n_edges;
         i += gridDim.x * blockDim.x) {
        atomicAdd(&deg[dst[i]], 1);
    }
}

// per-block reduce of a SCAN_CHUNK segment of deg
__global__ void scan_reduce_kernel(const int* __restrict__ deg, int n,
                                   int* __restrict__ blocksum) {
    __shared__ int tmp[SCAN_BLOCK];
    int b = blockIdx.x;
    int base = b * SCAN_CHUNK + threadIdx.x * 4;
    int s = 0;
    #pragma unroll
    for (int k = 0; k < 4; ++k) {
        int i = base + k;
        if (i < n) s += deg[i];
    }
    tmp[threadIdx.x] = s;
    __syncthreads();
    for (int ofs = SCAN_BLOCK / 2; ofs > 0; ofs >>= 1) {
        if (threadIdx.x < ofs) tmp[threadIdx.x] += tmp[threadIdx.x + ofs];
        __syncthreads();
    }
    if (threadIdx.x == 0) blocksum[b] = tmp[0];
}

// single-block exclusive scan of blocksum (nb <= SCAN_BLOCK)
__global__ void scan_toplevel_kernel(const int* __restrict__ blocksum,
                                     int* __restrict__ blockoff, int nb) {
    __shared__ int tmp[SCAN_BLOCK];
    int t = threadIdx.x;
    int orig = (t < nb) ? blocksum[t] : 0;
    int v = orig;
    for (int ofs = 1; ofs < SCAN_BLOCK; ofs <<= 1) {
        tmp[t] = v;
        __syncthreads();
        if (t >= ofs) v += tmp[t - ofs];
        __syncthreads();
    }
    if (t < nb) blockoff[t] = v - orig;   // exclusive
}

// per-block exclusive scan, writes offsets and cursor copy
__global__ void scan_final_kernel(const int* __restrict__ deg,
                                  const int* __restrict__ blockoff,
                                  int* __restrict__ offsets,
                                  int* __restrict__ cursor, int n) {
    __shared__ int tmp[SCAN_BLOCK];
    int b = blockIdx.x, t = threadIdx.x;
    int base = b * SCAN_CHUNK + t * 4;
    int d[4];
    #pragma unroll
    for (int k = 0; k < 4; ++k) d[k] = (base + k < n) ? deg[base + k] : 0;
    int tsum = d[0] + d[1] + d[2] + d[3];
    int v = tsum;
    for (int ofs = 1; ofs < SCAN_BLOCK; ofs <<= 1) {
        tmp[t] = v;
        __syncthreads();
        if (t >= ofs) v += tmp[t - ofs];
        __syncthreads();
    }
    int run = v - tsum + blockoff[b];      // exclusive base for this thread
    #pragma unroll
    for (int k = 0; k < 4; ++k) {
        int i = base + k;
        if (i < n) {
            offsets[i] = run;
            cursor[i]  = run;
            run += d[k];
            if (i == n - 1) offsets[n] = run;  // total = n_edges
        }
    }
}

__global__ void bucket_scatter_kernel(const int* __restrict__ src,
                                      const int* __restrict__ dst,
                                      int* __restrict__ cursor,
                                      int* __restrict__ srcs_sorted,
                                      int n_edges) {
    for (int i = blockIdx.x * blockDim.x + threadIdx.x; i < n_edges;
         i += gridDim.x * blockDim.x) {
        int t = dst[i];
        int pos = atomicAdd(&cursor[t], 1);
        srcs_sorted[pos] = src[i];
    }
}

// 32 threads per node (one feature each); batch-load 32 edge srcs, shfl-broadcast
__global__ void gather_kernel(const float* __restrict__ h,
                              const int* __restrict__ srcs_sorted,
                              const int* __restrict__ offsets,
                              float* __restrict__ out, int n_nodes) {
    int node = blockIdx.x * (blockDim.x >> 5) + (threadIdx.x >> 5);
    if (node >= n_nodes) return;
    int d = threadIdx.x & 31;
    int beg = offsets[node];
    int end = offsets[node + 1];
    float v = 0.0f;
    for (int j0 = beg; j0 < end; j0 += 32) {
        int myidx = j0 + d;
        int s_my = (myidx < end) ? srcs_sorted[myidx] : 0;
        int cnt = min(32, end - j0);
        for (int k = 0; k < cnt; ++k) {
            int s = __shfl(s_my, k, 32);
            v += h[(size_t)s * D_FEAT + d];
        }
    }
    float deg = (float)(end - beg);
    out[(size_t)node * D_FEAT + d] = v / fmaxf(deg, 1.0f);
}

// ---------------- fallback (round-1 atomic path) if ws too small -------------
__global__ void zero_init_kernel(float* __restrict__ out, int out_n,
                                 float* __restrict__ deg, int n_nodes) {
    int total = out_n + n_nodes;
    for (int i = blockIdx.x * blockDim.x + threadIdx.x; i < total;
         i += gridDim.x * blockDim.x) {
        if (i < out_n) out[i] = 0.0f;
        else deg[i - out_n] = 0.0f;
    }
}
__global__ void scatter_kernel(const float* __restrict__ h,
                               const int* __restrict__ src,
                               const int* __restrict__ dst,
                               float* __restrict__ out,
                               float* __restrict__ deg, int n_edges) {
    long long tid = (long long)blockIdx.x * blockDim.x + threadIdx.x;
    long long total = (long long)n_edges * D_FEAT;
    if (tid >= total) return;
    int e = (int)(tid >> 5);
    int d = (int)(tid & 31);
    float v = h[(long long)src[e] * D_FEAT + d];
    atomicAdd(&out[(long long)dst[e] * D_FEAT + d], v);
    if (d == 0) atomicAdd(&deg[dst[e]], 1.0f);
}
__global__ void finalize_kernel(float* __restrict__ out,
                                const float* __restrict__ deg, int n_nodes) {
    int total = n_nodes * D_FEAT;
    for (int i = blockIdx.x * blockDim.x + threadIdx.x; i < total;
         i += gridDim.x * blockDim.x)
        out[i] = out[i] / fmaxf(deg[i >> 5], 1.0f);
}
// -----------------------------------------------------------------------------

extern "C" void kernel_launch(void* const* d_in, const int* in_sizes, int n_in,
                              void* d_out, int out_size, void* d_ws, size_t ws_size,
                              hipStream_t stream) {
    const float* h = (const float*)d_in[0];
    const int* src = (const int*)d_in[1];
    const int* dst = (const int*)d_in[2];
    float* out = (float*)d_out;

    int n_nodes = in_sizes[0] / D_FEAT;
    int n_edges = in_sizes[1];
    int nb = (n_nodes + SCAN_CHUNK - 1) / SCAN_CHUNK;   // 98 for N=100K

    // workspace layout (ints)
    size_t need = ((size_t)3 * n_nodes + 1 + 2 * nb + n_edges) * sizeof(int);
    if (ws_size < need || nb > SCAN_BLOCK) {
        // fallback: atomic scatter path (needs n_nodes floats)
        float* deg = (float*)d_ws;
        int total0 = n_nodes * D_FEAT + n_nodes;
        zero_init_kernel<<<min((total0 + 255) / 256, 2048), 256, 0, stream>>>(
            out, n_nodes * D_FEAT, deg, n_nodes);
        long long total = (long long)n_edges * D_FEAT;
        scatter_kernel<<<(int)((total + 255) / 256), 256, 0, stream>>>(
            h, src, dst, out, deg, n_edges);
        finalize_kernel<<<min((n_nodes * D_FEAT + 255) / 256, 2048), 256, 0,
                          stream>>>(out, deg, n_nodes);
        return;
    }

    int* wsI        = (int*)d_ws;
    int* deg        = wsI;                      // n_nodes
    int* offsets    = deg + n_nodes;            // n_nodes + 1
    int* cursor     = offsets + n_nodes + 1;    // n_nodes
    int* blocksum   = cursor + n_nodes;         // nb
    int* blockoff   = blocksum + nb;            // nb
    int* srcs_sorted= blockoff + nb;            // n_edges

    zero_i32_kernel<<<min((n_nodes + 255) / 256, 2048), 256, 0, stream>>>(deg, n_nodes);
    degree_kernel<<<2048, 256, 0, stream>>>(dst, deg, n_edges);
    scan_reduce_kernel<<<nb, SCAN_BLOCK, 0, stream>>>(deg, n_nodes, blocksum);
    scan_toplevel_kernel<<<1, SCAN_BLOCK, 0, stream>>>(blocksum, blockoff, nb);
    scan_final_kernel<<<nb, SCAN_BLOCK, 0, stream>>>(deg, blockoff, offsets, cursor, n_nodes);
    bucket_scatter_kernel<<<2048, 256, 0, stream>>>(src, dst, cursor, srcs_sorted, n_edges);

    int nodes_per_block = 256 / 32;  // 8
    int grid = (n_nodes + nodes_per_block - 1) / nodes_per_block;
    gather_kernel<<<grid, 256, 0, stream>>>(h, srcs_sorted, offsets, out, n_nodes);
}